// Round 11
// baseline (225.711 us; speedup 1.0000x reference)
//
#include <hip/hip_runtime.h>
#include <hip/hip_bf16.h>

// Problem constants
#define NNODES 4096
#define NEDGES 32768
#define CH 96
#define EPS 1e-5f
#define INV_SQRT3 0.57735026918962576f
#define ALPHA 0.125f

#define EB 32
#define NEBLK (NEDGES / EB)   // 1024 edge-blocks; k1 grid = 2048 (x2 u-halves)

// ws layout: msg [0,393216) fp32, stats [393216,393328),
// bf16 fragment mirrors at float index 393344
#define OFF_MSG 0
#define OFF_ST  393216
#define OFF_WSB 393344
#define WSB_W2_U16 (OFF_WSB * 2)
#define WSB_W1_U16 (WSB_W2_U16 + 524288)
#define WS_BYTES1 (393328 * 4)
#define WS_BYTES2 (393344 * 4 + 524288 * 2 + 16384 * 2)

typedef __attribute__((ext_vector_type(8))) short short8;
typedef __attribute__((ext_vector_type(4))) float floatx4;

__device__ __forceinline__ unsigned short f2bf(float f) {
  union { float f; unsigned int u; } v; v.f = f;
  return (unsigned short)((v.u + 0x7FFFu + ((v.u >> 16) & 1u)) >> 16);
}
__device__ __forceinline__ float bf2f(unsigned short u) {
  union { unsigned int i; float f; } v; v.i = ((unsigned int)u) << 16; return v.f;
}
__device__ __forceinline__ float fin(float x) {
  return (x == x && fabsf(x) < 1e30f) ? x : 0.f;
}
__device__ __forceinline__ float dlrelu(float g) {
  return (fabsf(g) <= 10.f) ? g : 0.01f * g;
}

// ---------------------------------------------------------------------------
// K0: pack w1/w2 to MFMA B-frag order (bf16) + zero msg/stats.
__global__ __launch_bounds__(256) void k0_prep(const float* w1, const float* w2,
                                               float* ws, int ok1, int ok2) {
  __shared__ float tile[128 * 16];
  const int t = threadIdx.x;
  const int b = blockIdx.x;
  unsigned short* wsu = (unsigned short*)ws;

  if (ok1) {
    for (int i = b * 256 + t; i < 393328; i += 256 * 256) ws[i] = 0.f;
  }
  if (ok2) {
    {
      const int T = b;
#pragma unroll
      for (int p = 0; p < 8; p++) {
        int k = p * 16 + (t >> 4), col = t & 15;
        tile[k * 16 + col] = w2[(size_t)k * 4096 + T * 16 + col];
      }
      __syncthreads();
      int s = t >> 6, lane = t & 63, q = (lane >> 4), cl = lane & 15;
      unsigned int r[4];
#pragma unroll
      for (int jj = 0; jj < 4; jj++) {
        int k0 = s * 32 + q * 8 + 2 * jj;
        unsigned int lo = f2bf(tile[k0 * 16 + cl]);
        unsigned int hi = f2bf(tile[(k0 + 1) * 16 + cl]);
        r[jj] = lo | (hi << 16);
      }
      *(uint4*)(wsu + WSB_W2_U16 + ((size_t)(T * 4 + s) * 64 + lane) * 8) =
          make_uint4(r[0], r[1], r[2], r[3]);
    }
    if (b < 8) {
      __syncthreads();
      const int T = b;
#pragma unroll
      for (int p = 0; p < 8; p++) {
        int k = p * 16 + (t >> 4), col = t & 15;
        tile[k * 16 + col] = w1[(size_t)k * 128 + T * 16 + col];
      }
      __syncthreads();
      int s = t >> 6, lane = t & 63, q = (lane >> 4), cl = lane & 15;
      unsigned int r[4];
#pragma unroll
      for (int jj = 0; jj < 4; jj++) {
        int k0 = s * 32 + q * 8 + 2 * jj;
        unsigned int lo = f2bf(tile[k0 * 16 + cl]);
        unsigned int hi = f2bf(tile[(k0 + 1) * 16 + cl]);
        r[jj] = lo | (hi << 16);
      }
      *(uint4*)(wsu + WSB_W1_U16 + ((size_t)(T * 4 + s) * 64 + lane) * 8) =
          make_uint4(r[0], r[1], r[2], r[3]);
    }
  }
}

// ---------------------------------------------------------------------------
// K1: fused edge pipeline. 2048 blocks = 1024 edge-blocks x 2 u-halves.
// Halving per-block u-range doubles resident blocks/CU (grid was the
// occupancy limiter at 1024); total w2 L2 traffic unchanged.
// __launch_bounds__(256,4): 128 VGPR+AGPR budget — proven no-spill config.
__global__ __launch_bounds__(256, 4) void k1_fused(const int* eidx, const float* na,
                                                   const float* ea, const float* esh,
                                                   const float* b1g, const float* b2g,
                                                   float* ws, int ok2) {
  if (!ok2) return;
  __shared__ __align__(16) unsigned short a_lds[EB * 161];  // bf16 activations
  __shared__ __align__(16) char ovl[8704];                  // hscr, then tmp|vv
  __shared__ float ss_lds[EB];
  __shared__ float sv_lds[EB][3];
  __shared__ int dst_lds[EB];
  __shared__ int src_lds[EB];
  unsigned short* hscr = (unsigned short*)ovl;   // [e][k] stride 136, bf16
  float* tmp_l = (float*)ovl;                    // [e][17] fp32
  float* vv_l  = (float*)(ovl + 2176);           // [e][49] fp32

  const int tid = threadIdx.x;
  const int lane = tid & 63;
  const int q = lane >> 4;
  const int cl = lane & 15;
  const int wv = tid >> 6;            // 0..3
  const int h = blockIdx.x & 1;       // u-half
  const int e0 = (blockIdx.x >> 1) * EB;
  unsigned short* wsu = (unsigned short*)ws;
  float* msg = ws;

  // ---- phase 0: edge meta + int64/int32 detection
  if (tid < EB) {
    int o = 0;
    for (int i = 1; i < 256; i += 2) o |= eidx[i];
    const int is64 = (o == 0);
    int e = e0 + tid;
    int s = is64 ? eidx[2 * e] : eidx[e];
    int d = is64 ? eidx[2 * (NEDGES + e)] : eidx[NEDGES + e];
    src_lds[tid] = s & (NNODES - 1);
    dst_lds[tid] = d & (NNODES - 1);
    float4 sh = *(const float4*)(esh + (size_t)e * 4);
    ss_lds[tid] = sh.x;
    sv_lds[tid][0] = sh.y; sv_lds[tid][1] = sh.z; sv_lds[tid][2] = sh.w;
  }
  __syncthreads();

  // ---- phase 1b: gather per-edge activations (bf16), range-restricted:
  // h0 needs i<64 (ss/vs inputs); h1 needs i>=42 (stage i>=32).
  if (h == 0) {
    for (int idx = tid; idx < EB * 64; idx += 256) {
      int e = idx >> 6, i = idx & 63;
      const float* x = na + (size_t)src_lds[e] * CH;
      float v;
      if (i < 48) v = x[i] * ss_lds[e];
      else {
        int ii = i - 48;
        v = (x[48 + 3 * ii] * sv_lds[e][0] + x[49 + 3 * ii] * sv_lds[e][1] +
             x[50 + 3 * ii] * sv_lds[e][2]) * INV_SQRT3;
      }
      a_lds[e * 161 + i] = f2bf(v);
    }
  } else {
    for (int idx = tid; idx < EB * 128; idx += 256) {
      int e = idx >> 7, i = 32 + (idx & 127);
      const float* x = na + (size_t)src_lds[e] * CH;
      float v;
      if (i < 48) v = x[i] * ss_lds[e];
      else if (i < 64) {
        int ii = i - 48;
        v = (x[48 + 3 * ii] * sv_lds[e][0] + x[49 + 3 * ii] * sv_lds[e][1] +
             x[50 + 3 * ii] * sv_lds[e][2]) * INV_SQRT3;
      } else if (i < 112) v = x[i - 64];
      else v = x[48 + (i - 112)];
      a_lds[e * 161 + i] = f2bf(v);
    }
  }

  // ---- phase 1c: GEMM1  h = relu(ea@w1+b1) -> hscr (2 tiles/wave)
  {
    short8 a1[2][4];
#pragma unroll
    for (int mt = 0; mt < 2; mt++)
#pragma unroll
      for (int ks = 0; ks < 4; ks++) {
        const float* src = ea + (size_t)(e0 + mt * 16 + cl) * 128 + ks * 32 + q * 8;
        float4 v0 = *(const float4*)src;
        float4 v1 = *(const float4*)(src + 4);
        union { short8 s; unsigned int u[4]; } pk;
        pk.u[0] = f2bf(v0.x) | ((unsigned)f2bf(v0.y) << 16);
        pk.u[1] = f2bf(v0.z) | ((unsigned)f2bf(v0.w) << 16);
        pk.u[2] = f2bf(v1.x) | ((unsigned)f2bf(v1.y) << 16);
        pk.u[3] = f2bf(v1.z) | ((unsigned)f2bf(v1.w) << 16);
        a1[mt][ks] = pk.s;
      }
    const short8* w1f = (const short8*)(wsu + WSB_W1_U16);
#pragma unroll
    for (int t = 0; t < 2; t++) {
      int nt = wv * 2 + t;
      int hcol = nt * 16 + cl;
      float hb = b1g[hcol];
      floatx4 c0 = (floatx4)(hb), c1 = (floatx4)(hb);
#pragma unroll
      for (int ks = 0; ks < 4; ks++) {
        short8 bf = w1f[(nt * 4 + ks) * 64 + lane];
        c0 = __builtin_amdgcn_mfma_f32_16x16x32_bf16(a1[0][ks], bf, c0, 0, 0, 0);
        c1 = __builtin_amdgcn_mfma_f32_16x16x32_bf16(a1[1][ks], bf, c1, 0, 0, 0);
      }
#pragma unroll
      for (int r = 0; r < 4; r++) {
        hscr[(q * 4 + r) * 136 + hcol] = f2bf(fmaxf(c0[r], 0.f));
        hscr[(16 + q * 4 + r) * 136 + hcol] = f2bf(fmaxf(c1[r], 0.f));
      }
    }
  }
  __syncthreads();

  // ---- phase 2: A fragments (h) -> registers
  short8 areg[2][4];
#pragma unroll
  for (int mt = 0; mt < 2; mt++)
#pragma unroll
    for (int ks = 0; ks < 4; ks++)
      areg[mt][ks] = *(const short8*)&hscr[(mt * 16 + cl) * 136 + ks * 32 + q * 8];
  __syncthreads();   // hscr reads done; ovl reusable as tmp/vv

  // h1: zero tmp_l (shared by waves 2 and 3 -> LDS atomics)
  if (h == 1) {
    for (int idx = tid; idx < EB * 17; idx += 256) tmp_l[idx] = 0.f;
  }
  __syncthreads();

  // ---- phase 3: main loop, per-wave tile ranges, register B+bias prefetch
  const short8* w2f = (const short8*)(wsu + WSB_W2_U16);

#define LOADB(dst, bdst, uu) { const short8* _p = w2f + (size_t)((uu)&255) * 256 + lane; \
    dst[0] = _p[0]; dst[1] = _p[64]; dst[2] = _p[128]; dst[3] = _p[192]; \
    bdst = b2g[((uu)&255) * 16 + cl]; }

#define MFMA8(bb, bsc, c0, c1) \
    floatx4 c0 = (floatx4)(bsc), c1 = (floatx4)(bsc); \
    _Pragma("unroll") \
    for (int ks = 0; ks < 4; ks++) { \
      c0 = __builtin_amdgcn_mfma_f32_16x16x32_bf16(areg[0][ks], bb[ks], c0, 0, 0, 0); \
      c1 = __builtin_amdgcn_mfma_f32_16x16x32_bf16(areg[1][ks], bb[ks], c1, 0, 0, 0); }

  const int is_ss = (h == 0) || (wv < 2);
  if (is_ss) {
    // ss/vs class. h0: ai starts {0,11,22,32}, counts {11,11,10,10};
    // h1 (wv<2): starts {42,53}, counts {11,11}.  Total ai [0,64).
    const int base_ai = (h == 0) ? ((wv < 2) ? wv * 11 : 22 + (wv - 2) * 10)
                                 : 42 + wv * 11;
    const int ng = (h == 0 && wv >= 2) ? 10 : 11;
    const int u0 = base_ai * 3;
    float accS[3][2][4];
#pragma unroll
    for (int c = 0; c < 3; c++)
#pragma unroll
      for (int mt = 0; mt < 2; mt++)
#pragma unroll
        for (int r = 0; r < 4; r++) accS[c][mt][r] = 0.f;

    short8 b0[4], b1[4], b2[4];
    float bb0, bb1, bb2;
    LOADB(b0, bb0, u0); LOADB(b1, bb1, u0 + 1);
    for (int g = 0; g < ng; g++) {
      const int ai = base_ai + g;
      const int u = u0 + 3 * g;
      float av[2][4];
#pragma unroll
      for (int mt = 0; mt < 2; mt++)
#pragma unroll
        for (int r = 0; r < 4; r++)
          av[mt][r] = bf2f(a_lds[(mt * 16 + q * 4 + r) * 161 + ai]);

#define COMP_SS(bb, bsc, cidx) { \
      MFMA8(bb, bsc, c0, c1); \
      _Pragma("unroll") \
      for (int r = 0; r < 4; r++) { \
        accS[cidx][0][r] += av[0][r] * dlrelu(c0[r]); \
        accS[cidx][1][r] += av[1][r] * dlrelu(c1[r]); } }

      LOADB(b2, bb2, u + 2); COMP_SS(b0, bb0, 0);
      LOADB(b0, bb0, u + 3); COMP_SS(b1, bb1, 1);
      LOADB(b1, bb1, u + 4); COMP_SS(b2, bb2, 2);
    }
    // phase 4 (ss): direct global scatter, lane owns (e, c*16+cl)
#pragma unroll
    for (int mt = 0; mt < 2; mt++)
#pragma unroll
      for (int r = 0; r < 4; r++) {
        int e = mt * 16 + q * 4 + r;
        float* mrow = msg + (size_t)dst_lds[e] * CH;
#pragma unroll
        for (int c = 0; c < 3; c++)
          atomicAdd(mrow + c * 16 + cl, ALPHA * accS[c][mt][r]);
      }
  } else {
    // h1: wv2: sv u[192,228); wv3: sv u[228,240) + vv u[240,256)
    float accT[2][4], accV[2][4][3];
#pragma unroll
    for (int mt = 0; mt < 2; mt++)
#pragma unroll
      for (int r = 0; r < 4; r++) {
        accT[mt][r] = 0.f;
        accV[mt][r][0] = 0.f; accV[mt][r][1] = 0.f; accV[mt][r][2] = 0.f;
      }
    short8 b0[4], b1[4];
    float bb0, bb1;

#define COMP_SV(bb, bsc, uu) { \
    const int ai = (uu) - 128; \
    MFMA8(bb, bsc, c0, c1); \
    _Pragma("unroll") \
    for (int r = 0; r < 4; r++) { \
      accT[0][r] += bf2f(a_lds[(q * 4 + r) * 161 + ai]) * dlrelu(c0[r]); \
      accT[1][r] += bf2f(a_lds[(16 + q * 4 + r) * 161 + ai]) * dlrelu(c1[r]); } }

#define COMP_VV(bb, bsc, uu) { \
    const int ab = 3 * (uu) - 608; \
    MFMA8(bb, bsc, c0, c1); \
    _Pragma("unroll") \
    for (int r = 0; r < 4; r++) { \
      float w0 = dlrelu(c0[r]), w1v = dlrelu(c1[r]); \
      int ba0 = (q * 4 + r) * 161 + ab, ba1 = (16 + q * 4 + r) * 161 + ab; \
      accV[0][r][0] += bf2f(a_lds[ba0 + 0]) * w0; \
      accV[0][r][1] += bf2f(a_lds[ba0 + 1]) * w0; \
      accV[0][r][2] += bf2f(a_lds[ba0 + 2]) * w0; \
      accV[1][r][0] += bf2f(a_lds[ba1 + 0]) * w1v; \
      accV[1][r][1] += bf2f(a_lds[ba1 + 1]) * w1v; \
      accV[1][r][2] += bf2f(a_lds[ba1 + 2]) * w1v; } }

    if (wv == 2) {
      LOADB(b0, bb0, 192);
      for (int i = 0; i < 36; i += 2) {
        const int u = 192 + i;
        LOADB(b1, bb1, u + 1); COMP_SV(b0, bb0, u);
        LOADB(b0, bb0, u + 2); COMP_SV(b1, bb1, u + 1);
      }
    } else {
      LOADB(b0, bb0, 228);
      for (int i = 0; i < 12; i += 2) {
        const int u = 228 + i;
        LOADB(b1, bb1, u + 1); COMP_SV(b0, bb0, u);
        LOADB(b0, bb0, u + 2); COMP_SV(b1, bb1, u + 1);
      }
      for (int i = 0; i < 16; i += 2) {
        const int u = 240 + i;
        LOADB(b1, bb1, u + 1); COMP_VV(b0, bb0, u);
        LOADB(b0, bb0, u + 2); COMP_VV(b1, bb1, u + 1);
      }
    }
    // phase 4 (sv/vv): tmp shared by wv2/wv3 -> LDS atomics; vv wv3-only
#pragma unroll
    for (int mt = 0; mt < 2; mt++)
#pragma unroll
      for (int r = 0; r < 4; r++) {
        int e = mt * 16 + q * 4 + r;
        atomicAdd(&tmp_l[e * 17 + cl], accT[mt][r]);
        if (wv == 3) {
#pragma unroll
          for (int m = 0; m < 3; m++)
            vv_l[e * 49 + 3 * cl + m] = accV[mt][r][m];
        }
      }
  }
  __syncthreads();

  // ---- phase 5 (h1 only): v-channels scatter
  if (h == 1) {
    for (int idx = tid; idx < EB * 48; idx += 256) {
      int e = idx / 48, t2 = idx - e * 48;
      int k = t2 / 3, m = t2 - k * 3;
      float val = ALPHA * (tmp_l[e * 17 + k] * sv_lds[e][m] +
                           ss_lds[e] * vv_l[e * 49 + 3 * k + m]);
      atomicAdd(msg + (size_t)dst_lds[e] * CH + 48 + t2, val);
    }
  }
}

// ---------------------------------------------------------------------------
__global__ __launch_bounds__(256) void k2_stats(const float* na, float* ws, int ok1) {
  __shared__ float part[112];
  const float* msg = ws + OFF_MSG;
  float* st = ws + OFF_ST;
  for (int i = threadIdx.x; i < 112; i += 256) part[i] = 0.f;
  __syncthreads();
  if (ok1) {
    int stride = gridDim.x * 256;
    for (int idx = blockIdx.x * 256 + threadIdx.x; idx < NNODES * CH; idx += stride) {
      int c = idx % CH;
      float t = msg[idx] + na[idx];
      if (c < 48) { atomicAdd(&part[c], t); atomicAdd(&part[48 + c], t * t); }
      else { int k = (c - 48) / 3; atomicAdd(&part[96 + k], t * t); }
    }
    __syncthreads();
    for (int i = threadIdx.x; i < 112; i += 256) atomicAdd(&st[i], part[i]);
  }
}

// ---------------------------------------------------------------------------
__global__ __launch_bounds__(256) void k3_final(const float* na, const float* bnw,
                                                const float* bnb, const float* ws,
                                                float* out, int ok1) {
  __shared__ float mean_s[48], scale_s[48], bias_s[48], scale_v[16];
  const float* msg = ws + OFF_MSG;
  const float* st = ws + OFF_ST;
  const int tid = threadIdx.x;
  if (tid < 48) {
    float s1 = ok1 ? fin(st[tid]) : 0.f;
    float s2 = ok1 ? fin(st[48 + tid]) : 0.f;
    float m = s1 * (1.f / NNODES);
    float var = fmaxf(s2 * (1.f / NNODES) - m * m, 0.f);
    mean_s[tid] = m;
    scale_s[tid] = rsqrtf(var + EPS) * bnw[tid];
    bias_s[tid] = bnb[tid];
  } else if (tid < 64) {
    int k = tid - 48;
    float s2 = ok1 ? fin(st[96 + k]) : 0.f;
    scale_v[k] = rsqrtf(fmaxf(s2 * (1.f / (3.f * NNODES)), 0.f) + EPS) * bnw[48 + k];
  }
  __syncthreads();
  int stride = gridDim.x * 256;
  for (int idx = blockIdx.x * 256 + tid; idx < NNODES * CH; idx += stride) {
    int c = idx % CH;
    float t = (ok1 ? msg[idx] : 0.f) + na[idx];
    float o;
    if (c < 48) o = (t - mean_s[c]) * scale_s[c] + bias_s[c];
    else { int k = (c - 48) / 3; o = t * scale_v[k]; }
    out[idx] = fin(o);
  }
}

// ---------------------------------------------------------------------------
extern "C" void kernel_launch(void* const* d_in, const int* in_sizes, int n_in,
                              void* d_out, int out_size, void* d_ws, size_t ws_size,
                              hipStream_t stream) {
  const float* na  = (const float*)d_in[0];
  const int* eidx  = (const int*)d_in[1];
  const float* ea  = (const float*)d_in[2];
  const float* esh = (const float*)d_in[3];
  const float* w1  = (const float*)d_in[4];
  const float* b1  = (const float*)d_in[5];
  const float* w2  = (const float*)d_in[6];
  const float* b2  = (const float*)d_in[7];
  const float* bnw = (const float*)d_in[8];
  const float* bnb = (const float*)d_in[9];
  float* out = (float*)d_out;
  float* ws = (float*)d_ws;
  const int ok1 = (ws_size >= (size_t)WS_BYTES1) ? 1 : 0;
  const int ok2 = (ws_size >= (size_t)WS_BYTES2) ? 1 : 0;

  hipLaunchKernelGGL(k0_prep,  dim3(256), dim3(256), 0, stream, w1, w2, ws, ok1, ok2);
  hipLaunchKernelGGL(k1_fused, dim3(NEBLK * 2), dim3(256), 0, stream,
                     eidx, na, ea, esh, b1, b2, ws, ok2);
  hipLaunchKernelGGL(k2_stats, dim3(512), dim3(256), 0, stream, na, ws, ok1);
  hipLaunchKernelGGL(k3_final, dim3(512), dim3(256), 0, stream, na, bnw, bnb, ws, out, ok1);
}